// Round 7
// baseline (200.684 us; speedup 1.0000x reference)
//
#include <hip/hip_runtime.h>

typedef __bf16 bf16x8 __attribute__((ext_vector_type(8)));
typedef float  floatx16 __attribute__((ext_vector_type(16)));

#define HW   56
#define NPIX 3136
#define CIN  128
#define COUT 256

#define AS_GLOBAL __attribute__((address_space(1)))
#define AS_LDS    __attribute__((address_space(3)))

// W2 layout: [cc(4)][tap(9)][cg(4)][oc(256)][j(8)], bf16. 576 KB of d_ws.
__global__ __launch_bounds__(256) void wt_transform_kernel(
        const float* __restrict__ Kw, __bf16* __restrict__ W2) {
    int idx = blockIdx.x * 256 + threadIdx.x;     // coalesced write
    int j     = idx & 7;
    int oc    = (idx >> 3) & 255;
    int cg    = (idx >> 11) & 3;
    int tapcc = idx >> 13;                        // cc*9 + tap
    int tap   = tapcc % 9;
    int cc    = tapcc / 9;
    int c = cc * 32 + cg * 8 + j;
    W2[idx] = (__bf16)Kw[oc * 1152 + c * 9 + tap];
}

// Xs: [buf(2)][row(6)][wp(66)][slot(40)] bf16; slots 0..31 = ci, 32..39 pad.
// Stride 40 elems = 80 B: bank-base advances 20 banks/wp -> conflict-free b128.
__device__ __forceinline__ int xs_idx(int row, int wp, int cg) {
    return row * 2640 + wp * 40 + cg * 8;
}

// R9: fuse x-staging into the tap pipeline. R8 ruled out barrier count; the
// remaining serial phase is staging (HBM-latency loads + cvt + full-drain
// syncthreads, 4x per block, nothing overlaps). Now: Xs double-buffered
// (2x31.7 KB), A 2-slot per-tap DMA rotation (2x8 KB, R6-equivalent depth-1),
// and next-cc x rows issued at taps 2/4/6 (8 unconditional clamped loads ->
// wave-uniform vmcnt counts), written to the other Xs at taps 3/5/7 (~600 cyc
// later, hidden under MFMAs; 8-VGPR transient, 1-tap live range — unlike R3's
// 32-reg 4-deep buffer that spilled). cc boundaries become ordinary tap
// transitions: zero dedicated staging phases, zero full-drain syncthreads in
// the main loop. vmcnt bookkeeping: at tap t in {3,5,7} the staging row (8
// dwords) is newer than the awaited A-DMA -> vmcnt(8); else vmcnt(0);
// lgkmcnt(0) at cc-boundary for cross-wave ds_write visibility.
// LDS 63.4+16 = 79.7 KB -> still 2 blocks/CU; regs ~124+8 vs 128 cap (watch
// WRITE_SIZE/VGPR for spill alarm).
__global__ __launch_bounds__(512, 4) void conv_kernel(
        const float* __restrict__ x, const __bf16* __restrict__ W2,
        const float* __restrict__ bias, float* __restrict__ out) {
    __shared__ __align__(16) __bf16 Xs[2][6 * 2640];   // 2 x 31.68 KB
    __shared__ __align__(16) __bf16 Abuf[2][4096];     // 2 x 8 KB tap slices

    const int t    = threadIdx.x;
    const int nb   = blockIdx.x / 14;
    const int ht   = blockIdx.x % 14;
    const int h0   = ht * 4;
    const int ocb  = blockIdx.y * 128;

    const int wid  = t >> 6;          // 0..7
    const int lane = t & 63;
    const int half = lane >> 5;
    const int l31  = lane & 31;

    const int oc_rel = (wid & 1) * 64;          // wave's 64-oc slice within block
    const int prow   = wid >> 1;                // wave's output row (0..3)
    const int aocc   = (oc_rel + l31) * 8;      // A_lds elem base for this lane

    floatx16 acc[2][2];
    #pragma unroll
    for (int mi = 0; mi < 2; ++mi)
        #pragma unroll
        for (int nj = 0; nj < 2; ++nj)
            #pragma unroll
            for (int k = 0; k < 16; ++k)
                acc[mi][nj][k] = 0.f;

    // Zero halo columns wp==0 and wp in [57,66) for BOTH buffers (halo slots
    // are never rewritten; staging touches wp 1..56 only).
    if (t < 240) {
        int cg   = t & 3;
        int rest = t >> 2;            // 0..59
        int row  = rest / 10;
        int zw   = rest % 10;
        int wp   = (zw == 0) ? 0 : (56 + zw);
        *(int4*)&Xs[0][xs_idx(row, wp, cg)] = make_int4(0, 0, 0, 0);
        *(int4*)&Xs[1][xs_idx(row, wp, cg)] = make_int4(0, 0, 0, 0);
    }

    // DMA one 8 KB W2 g-slice (g = cc*9+tap) -> Abuf[buf]. One
    // global_load_lds_dwordx4 per thread; LDS dest linear t*16.
    auto dma_a = [&](int g, int buf) {
        const __bf16* src = W2 + (size_t)g * 8192
                          + (t >> 7) * 2048 + (size_t)(ocb + (t & 127)) * 8;
        __builtin_amdgcn_global_load_lds(
            (const AS_GLOBAL unsigned*)(const void*)src,
            (AS_LDS unsigned*)(void*)&Abuf[buf][t * 8], 16, 0, 0);
    };

    // Staging map: t -> (w = t&63, cg = (t>>6)&3, rowgroup = t>>8); 3 rows/thr.
    const int  sw     = t & 63;
    const int  sgr    = t >> 6;       // 0..7
    const int  sg     = sgr & 3;      // cg, uniform per wave -> clean b128 writes
    const int  rg2    = sgr >> 2;     // 0/1 row-group
    const bool wvalid = sw < 56;
    const int  swc    = sw < 55 ? sw : 55;   // clamped (unconditional loads)

    // Prologue: synchronous stage of cc=0 into Xs[0]; A(0) DMA; full drain.
    #pragma unroll
    for (int p = 0; p < 3; ++p) {
        int row = rg2 * 3 + p;
        int hin = h0 - 1 + row;
        bf16x8 v;
        #pragma unroll
        for (int j = 0; j < 8; ++j) v[j] = (__bf16)0.f;
        if (wvalid && (unsigned)hin < 56u) {
            const float* src = x + (size_t)(nb * CIN + sg * 8) * NPIX + hin * HW + sw;
            #pragma unroll
            for (int j = 0; j < 8; ++j)
                v[j] = (__bf16)src[j * NPIX];
        }
        if (wvalid)
            *(bf16x8*)&Xs[0][xs_idx(row, 1 + sw, sg)] = v;
    }
    dma_a(0, 0);
    __syncthreads();

    for (int cc = 0; cc < 4; ++cc) {
        const __bf16* Xcur = &Xs[cc & 1][0];
        __bf16*       Xoth = &Xs[(cc & 1) ^ 1][0];
        const bool do_stg = (cc < 3);
        // Source base for NEXT cc's channels (clamped, unconditional loads).
        const float* sx = x + (size_t)(nb * CIN + (cc + 1) * 32 + sg * 8) * NPIX;

        float sreg[8];                // 1-tap live range (issue t -> write t+1)

        #pragma unroll
        for (int tap = 0; tap < 9; ++tap) {
            const int g = cc * 9 + tap;

            // ---- wait own A(g) DMA chunk, then barrier ----
            if (tap == 0) {
                if (cc > 0) {
                    // lgkmcnt(0): make this wave's tap-7 ds_writes to Xcur
                    // (written as Xoth last cc) visible across the barrier.
                    asm volatile("s_waitcnt vmcnt(0) lgkmcnt(0)" ::: "memory");
                    __builtin_amdgcn_s_barrier();
                }
            } else {
                if (do_stg && (tap == 3 || tap == 5 || tap == 7))
                    asm volatile("s_waitcnt vmcnt(8)" ::: "memory");  // 8 stg dwords newer
                else
                    asm volatile("s_waitcnt vmcnt(0)" ::: "memory");
                __builtin_amdgcn_s_barrier();
            }

            // ---- deferred staging write (row issued last tap) ----
            if (do_stg && (tap == 3 || tap == 5 || tap == 7)) {
                const int p   = (tap - 3) / 2;
                const int row = rg2 * 3 + p;
                const int hin = h0 - 1 + row;
                const bool hv = (unsigned)hin < 56u;
                bf16x8 v;
                #pragma unroll
                for (int j = 0; j < 8; ++j)
                    v[j] = (__bf16)(hv ? sreg[j] : 0.f);
                if (wvalid)
                    *(bf16x8*)&Xoth[xs_idx(row, 1 + sw, sg)] = v;
            }

            // ---- next A DMA (target buffer freed by the barrier above) ----
            if (g < 35) dma_a(g + 1, (g + 1) & 1);

            // ---- issue next staging row (clamped, unconditional) ----
            if (do_stg && (tap == 2 || tap == 4 || tap == 6)) {
                const int p   = (tap - 2) / 2;
                const int row = rg2 * 3 + p;
                const int hin = h0 - 1 + row;
                const int hc  = hin < 0 ? 0 : (hin > 55 ? 55 : hin);
                const float* srcp = sx + hc * HW + swc;
                #pragma unroll
                for (int j = 0; j < 8; ++j)
                    sreg[j] = srcp[j * NPIX];
            }

            // ---- compute this tap ----
            {
                const int r = tap / 3, s = tap % 3;
                const __bf16* At = &Abuf[g & 1][0];
                __builtin_amdgcn_s_setprio(1);
                #pragma unroll
                for (int kc = 0; kc < 2; ++kc) {
                    bf16x8 afr[2];
                    #pragma unroll
                    for (int mi = 0; mi < 2; ++mi)
                        afr[mi] = *(const bf16x8*)&At[(kc * 2 + half) * 1024 + aocc + mi * 256];
                    bf16x8 bfr[2];
                    #pragma unroll
                    for (int nj = 0; nj < 2; ++nj)
                        bfr[nj] = *(const bf16x8*)&Xcur[xs_idx(prow + r, nj * 32 + l31 + s,
                                                               kc * 2 + half)];
                    #pragma unroll
                    for (int mi = 0; mi < 2; ++mi)
                        #pragma unroll
                        for (int nj = 0; nj < 2; ++nj)
                            acc[mi][nj] = __builtin_amdgcn_mfma_f32_32x32x16_bf16(
                                afr[mi], bfr[nj], acc[mi][nj], 0, 0, 0);
                }
                __builtin_amdgcn_s_setprio(0);
            }
        }
    }

    // Epilogue: C/D 32x32 layout col=lane&31 (pos), row=(rg&3)+8*(rg>>2)+4*half (oc).
    const float bv = bias[0];
    const int hout = h0 + prow;
    const int oc_base = ocb + oc_rel;
    #pragma unroll
    for (int nj = 0; nj < 2; ++nj) {
        int pw = nj * 32 + l31;
        if (pw < 56) {
            #pragma unroll
            for (int mi = 0; mi < 2; ++mi) {
                #pragma unroll
                for (int rg = 0; rg < 16; ++rg) {
                    int oc = oc_base + mi * 32 + (rg & 3) + ((rg >> 2) << 3) + half * 4;
                    out[(size_t)(nb * COUT + oc) * NPIX + hout * HW + pw] = acc[mi][nj][rg] + bv;
                }
            }
        }
    }
}

extern "C" void kernel_launch(void* const* d_in, const int* in_sizes, int n_in,
                              void* d_out, int out_size, void* d_ws, size_t ws_size,
                              hipStream_t stream) {
    const float* x    = (const float*)d_in[0];
    const float* Kw   = (const float*)d_in[1];
    const float* bias = (const float*)d_in[2];
    float* out = (float*)d_out;
    __bf16* W2 = (__bf16*)d_ws;   // needs 589824 bytes of workspace

    wt_transform_kernel<<<dim3(1152), dim3(256), 0, stream>>>(Kw, W2);
    conv_kernel<<<dim3(32 * 14, 2), dim3(512), 0, stream>>>(x, W2, bias, out);
}